// Round 6
// baseline (143.637 us; speedup 1.0000x reference)
//
#include <hip/hip_runtime.h>

typedef _Float16 f16;
typedef _Float16 f16x2 __attribute__((ext_vector_type(2)));
typedef _Float16 f16x4 __attribute__((ext_vector_type(4)));
typedef _Float16 f16x8 __attribute__((ext_vector_type(8)));
typedef float    f32x4 __attribute__((ext_vector_type(4)));
typedef int      i32x4 __attribute__((ext_vector_type(4)));

#define NHEADS 16
#define DK 64
#define BATCH 2
#define SEQ 2048
#define DMODEL 1024
#define MTOT (BATCH*SEQ)          // 4096
#define NQKV (3*DMODEL)           // 3072
#define LOG2E 1.44269504f
#define QSCALE (0.125f * LOG2E)   // fold 1/sqrt(dk) and log2(e) into Q
#define MASKVAL (-10000.0f * LOG2E)

__device__ inline f16x8 ld_f16x8_g(const f16* p) {
  return __builtin_bit_cast(f16x8, *reinterpret_cast<const i32x4*>(p));
}

__device__ inline f16x2 cvt_pk(float a, float b) {
  return __builtin_bit_cast(f16x2, __builtin_amdgcn_cvt_pkrtz(a, b));
}

__device__ inline void gl_lds16(const void* g, void* l) {
  __builtin_amdgcn_global_load_lds(
      (const __attribute__((address_space(1))) unsigned int*)g,
      (__attribute__((address_space(3))) unsigned int*)l, 16, 0, 0);
}

// ---------------- convert f32 -> f16, elementwise (n % 4 == 0) ----------------
__global__ void k_cvt(const float* __restrict__ in, f16* __restrict__ out, int n) {
  int i = (blockIdx.x * blockDim.x + threadIdx.x) * 4;
  if (i >= n) return;
  float4 v = *reinterpret_cast<const float4*>(in + i);
  f16x4 o = { (f16)v.x, (f16)v.y, (f16)v.z, (f16)v.w };
  *reinterpret_cast<f16x4*>(out + i) = o;
}

// ---------------- mask -> additive f32 bias in exp2 domain ----------------
__global__ void k_maskb(const int* __restrict__ mask, float* __restrict__ mb, int n) {
  int i = blockIdx.x * blockDim.x + threadIdx.x;
  if (i < n) mb[i] = mask[i] ? 0.f : MASKVAL;
}

// ------- transpose + convert: in f32 [K][N] -> out f16 [N][K] (K,N % 32 == 0) -------
__global__ void k_tcvt(const float* __restrict__ in, f16* __restrict__ out, int K, int N) {
  __shared__ float tile[32][33];
  int k0 = blockIdx.y * 32, n0 = blockIdx.x * 32;
  int tx = threadIdx.x, ty = threadIdx.y;   // block (32,8)
  #pragma unroll
  for (int i = 0; i < 4; ++i)
    tile[ty + 8*i][tx] = in[(size_t)(k0 + ty + 8*i) * N + n0 + tx];
  __syncthreads();
  #pragma unroll
  for (int i = 0; i < 4; ++i)
    out[(size_t)(n0 + ty + 8*i) * K + k0 + tx] = (f16)tile[tx][ty + 8*i];
}

// ---------------- GEMM: C[M,N] = A[M,K](f16) * Bt[N,K]^T(f16) + bias ----------------
template<int EPI>
__global__ __launch_bounds__(256, 2) void k_gemm(
    const f16* __restrict__ A, const f16* __restrict__ Bt,
    const float* __restrict__ bias,
    f16* __restrict__ qo, f16* __restrict__ ko, f16* __restrict__ vto,
    float* __restrict__ outf, int M, int N, int K)
{
  __shared__ f16 As[128][72];
  __shared__ f16 Bs[128][72];
  const int m0 = blockIdx.y * 128, n0 = blockIdx.x * 128;
  const int t = threadIdx.x;
  const int l = t & 63, w = t >> 6;
  const int wr = w >> 1, wc = w & 1;
  const int lc = l & 15, lk = (l >> 4) * 8;

  f32x4 acc[4][4] = {};

  for (int kt = 0; kt < K; kt += 64) {
    #pragma unroll
    for (int it = 0; it < 4; ++it) {
      int idx = it * 256 + t;
      int row = idx >> 3, c8 = (idx & 7) * 8;
      *reinterpret_cast<i32x4*>(&As[row][c8]) =
        *reinterpret_cast<const i32x4*>(A + (size_t)(m0 + row) * K + kt + c8);
      *reinterpret_cast<i32x4*>(&Bs[row][c8]) =
        *reinterpret_cast<const i32x4*>(Bt + (size_t)(n0 + row) * K + kt + c8);
    }
    __syncthreads();
    #pragma unroll
    for (int ks = 0; ks < 64; ks += 32) {
      f16x8 af[4], bf[4];
      #pragma unroll
      for (int i = 0; i < 4; ++i)
        af[i] = __builtin_bit_cast(f16x8, *reinterpret_cast<i32x4*>(&As[wr*64 + i*16 + lc][ks + lk]));
      #pragma unroll
      for (int j = 0; j < 4; ++j)
        bf[j] = __builtin_bit_cast(f16x8, *reinterpret_cast<i32x4*>(&Bs[wc*64 + j*16 + lc][ks + lk]));
      #pragma unroll
      for (int i = 0; i < 4; ++i)
        #pragma unroll
        for (int j = 0; j < 4; ++j)
          acc[i][j] = __builtin_amdgcn_mfma_f32_16x16x32_f16(af[i], bf[j], acc[i][j], 0, 0, 0);
    }
    __syncthreads();
  }

  const int lr4 = (l >> 4) * 4;   // C/D: row = (l>>4)*4 + r, col = l&15
  #pragma unroll
  for (int i = 0; i < 4; ++i) {
    #pragma unroll
    for (int j = 0; j < 4; ++j) {
      int col = n0 + wc*64 + j*16 + lc;
      float bv = bias[col];
      #pragma unroll
      for (int r = 0; r < 4; ++r) {
        int row = m0 + wr*64 + i*16 + lr4 + r;
        float v = acc[i][j][r] + bv;
        if (EPI == 0) {
          int which = col >> 10, h = (col >> 6) & 15, d = col & 63;
          int b = row >> 11, s = row & (SEQ - 1);
          size_t bh = (size_t)(b * NHEADS + h);
          if (which == 0)      qo[(bh * SEQ + s) * DK + d] = (f16)(v * QSCALE);
          else if (which == 1) ko[(bh * SEQ + s) * DK + d] = (f16)v;
          else {
            // V^T stored with kappa-permuted s within each 64-tile:
            // kappa(k) = (k&32) | ((k&12)<<1) | ((k&16)>>2) | (k&3)
            int sp = (s & ~63) | (s & 32) | ((s & 12) << 1) | ((s & 16) >> 2) | (s & 3);
            vto[(bh * DK + d) * SEQ + sp] = (f16)v;
          }
        } else {
          outf[(size_t)row * N + col] = v;
        }
      }
    }
  }
}

// ---------------- flash attention v5 ----------------
// 1024 blocks of 128 threads = 32 (b,h) * 32 q-blocks of 64; 2 waves, wave owns
// 32 q rows (2 q-tiles) -> each K/V LDS fragment read feeds 2 MFMA (halved LDS
// issue vs v4). P in registers (kappa V), mask bias in QK C-init, XCD swizzle.
__global__ __launch_bounds__(128, 2) void k_attn5(
    const f16* __restrict__ Q, const f16* __restrict__ K,
    const f16* __restrict__ Vt, const float* __restrict__ mbias,
    f16* __restrict__ ctx)
{
  __shared__ f16 Kb[2][64][64];
  __shared__ f16 Vb[2][64][64];

  // XCD-aware remap: bid%8 = XCD; each XCD owns 4 whole heads.
  const int bid = blockIdx.x;
  const int xcd = bid & 7, slot = bid >> 3;        // slot 0..127
  const int bh = xcd * 4 + (slot >> 5);            // 0..31
  const int qb = slot & 31;
  const int b  = bh >> 4, h = bh & (NHEADS - 1);
  const int t = threadIdx.x, l = t & 63, w = t >> 6;   // w in {0,1}
  const int lc = l & 15, g = l >> 4;
  const int q0 = qb * 64 + w * 32;

  const f16* Qp = Q + (size_t)bh * SEQ * DK;
  const f16* Kp = K + (size_t)bh * SEQ * DK;
  const f16* Vp = Vt + (size_t)bh * DK * SEQ;
  const float* mp = mbias + b * SEQ;

  // Q B-frags: 2 q-tiles (col = q = lc), kept in regs
  f16x8 qf[2][2];
  #pragma unroll
  for (int qt = 0; qt < 2; ++qt)
    #pragma unroll
    for (int s = 0; s < 2; ++s)
      qf[qt][s] = ld_f16x8_g(Qp + (size_t)(q0 + qt*16 + lc) * DK + s*32 + g*8);

  f32x4 o[2][4] = {};            // O^T acc [q-tile][d-tile]
  float mrow[2] = {-3e38f, -3e38f};
  f32x4 ls[2] = {{0.f,0.f,0.f,0.f},{0.f,0.f,0.f,0.f}};

  const int srow = l >> 3;                 // staging row within 8-row stripe
  const int ssl  = ((l & 7) ^ srow) * 16;  // inverse-swizzled source slot
  const int swz  = (lc & 7) << 4;          // read-side XOR

  auto do_stage = [&](int buf, int kt) {
    #pragma unroll
    for (int p = 0; p < 4; ++p) {
      int r = w*32 + p*8 + srow;
      gl_lds16((const char*)Kp + (size_t)(kt + r) * (DK*2) + ssl,
               &Kb[buf][w*32 + p*8][0]);
      gl_lds16((const char*)Vp + (size_t)r * (SEQ*2) + (size_t)kt*2 + ssl,
               &Vb[buf][w*32 + p*8][0]);
    }
  };

  constexpr int NT = SEQ / 64;
  do_stage(0, 0);

  float4 b4[4];
  #pragma unroll
  for (int c = 0; c < 4; ++c)
    b4[c] = *reinterpret_cast<const float4*>(mp + c*16 + g*4);

  for (int it = 0; it < NT; ++it) {
    __syncthreads();
    if (it + 1 < NT) do_stage((it + 1) & 1, (it + 1) * 64);

    // --- S^T = K * Q^T + maskbias (rows = k, cols = q), 2 q-tiles ---
    f32x4 p[2][4];
    #pragma unroll
    for (int qt = 0; qt < 2; ++qt)
      #pragma unroll
      for (int c = 0; c < 4; ++c)
        p[qt][c] = f32x4{b4[c].x, b4[c].y, b4[c].z, b4[c].w};
    const char* kb = (const char*)&Kb[it & 1][0][0];
    #pragma unroll
    for (int c = 0; c < 4; ++c) {
      const char* kr = kb + (c*16 + lc) * 128;
      f16x8 k0 = *(const f16x8*)(kr + ((g*16) ^ swz));
      f16x8 k1 = *(const f16x8*)(kr + ((64 + g*16) ^ swz));
      #pragma unroll
      for (int qt = 0; qt < 2; ++qt) {
        p[qt][c] = __builtin_amdgcn_mfma_f32_16x16x32_f16(k0, qf[qt][0], p[qt][c], 0, 0, 0);
        p[qt][c] = __builtin_amdgcn_mfma_f32_16x16x32_f16(k1, qf[qt][1], p[qt][c], 0, 0, 0);
      }
    }

    // preload next tile's bias (covered by softmax+PV latency)
    if (it + 1 < NT) {
      const float* mn = mp + (it + 1) * 64;
      #pragma unroll
      for (int c = 0; c < 4; ++c)
        b4[c] = *reinterpret_cast<const float4*>(mn + c*16 + g*4);
    }

    // --- online softmax (defer-max T13, THR=8 in log2 domain) ---
    float mx[2];
    #pragma unroll
    for (int qt = 0; qt < 2; ++qt) {
      f32x4 m4 = p[qt][0];
      #pragma unroll
      for (int c = 1; c < 4; ++c)
        #pragma unroll
        for (int r = 0; r < 4; ++r) m4[r] = fmaxf(m4[r], p[qt][c][r]);
      mx[qt] = fmaxf(fmaxf(m4[0], m4[1]), fmaxf(m4[2], m4[3]));
    }

    if (!__all(mx[0] <= mrow[0] + 8.f && mx[1] <= mrow[1] + 8.f)) {
      #pragma unroll
      for (int qt = 0; qt < 2; ++qt) {
        float v = mx[qt];
        v = fmaxf(v, __shfl_xor(v, 16));
        v = fmaxf(v, __shfl_xor(v, 32));
        float nm = fmaxf(mrow[qt], v);
        float sc = __builtin_amdgcn_exp2f(mrow[qt] - nm);
        mrow[qt] = nm;
        #pragma unroll
        for (int r = 0; r < 4; ++r) ls[qt][r] *= sc;
        #pragma unroll
        for (int dt = 0; dt < 4; ++dt)
          #pragma unroll
          for (int r = 0; r < 4; ++r) o[qt][dt][r] *= sc;
      }
    }

    // --- P = exp2(S - m), vector row-sum, pack in-register ---
    f16x4 h4[2][4];
    #pragma unroll
    for (int qt = 0; qt < 2; ++qt)
      #pragma unroll
      for (int c = 0; c < 4; ++c) {
        f32x4 e;
        #pragma unroll
        for (int r = 0; r < 4; ++r) e[r] = __builtin_amdgcn_exp2f(p[qt][c][r] - mrow[qt]);
        #pragma unroll
        for (int r = 0; r < 4; ++r) ls[qt][r] += e[r];
        union { f16x2 h2[2]; f16x4 h4v; } u;
        u.h2[0] = cvt_pk(e[0], e[1]);
        u.h2[1] = cvt_pk(e[2], e[3]);
        h4[qt][c] = u.h4v;
      }

    // --- O^T += V^T * P : B-frag is lane-local [h4[2ch] | h4[2ch+1]] ---
    const char* vb = (const char*)&Vb[it & 1][0][0];
    #pragma unroll
    for (int ch = 0; ch < 2; ++ch) {
      f16x8 pf[2];
      #pragma unroll
      for (int qt = 0; qt < 2; ++qt) {
        union { f16x4 q[2]; f16x8 v8; } upf;
        upf.q[0] = h4[qt][2*ch]; upf.q[1] = h4[qt][2*ch + 1];
        pf[qt] = upf.v8;
      }
      #pragma unroll
      for (int dt = 0; dt < 4; ++dt) {
        const char* vr = vb + (dt*16 + lc) * 128;
        f16x8 vf = *(const f16x8*)(vr + ((ch*64 + g*16) ^ swz));
        #pragma unroll
        for (int qt = 0; qt < 2; ++qt)
          o[qt][dt] = __builtin_amdgcn_mfma_f32_16x16x32_f16(vf, pf[qt], o[qt][dt], 0, 0, 0);
      }
    }
  }

  // --- finalize per q-tile ---
  #pragma unroll
  for (int qt = 0; qt < 2; ++qt) {
    float s = (ls[qt][0] + ls[qt][1]) + (ls[qt][2] + ls[qt][3]);
    s += __shfl_xor(s, 16);
    s += __shfl_xor(s, 32);
    float inv = 1.f / s;
    #pragma unroll
    for (int dt = 0; dt < 4; ++dt) {
      union { f16x2 h2[2]; f16x4 h4v; } u;
      u.h2[0] = cvt_pk(o[qt][dt][0]*inv, o[qt][dt][1]*inv);
      u.h2[1] = cvt_pk(o[qt][dt][2]*inv, o[qt][dt][3]*inv);
      *(f16x4*)(ctx + (size_t)(b*SEQ + q0 + qt*16 + lc) * DMODEL + h*DK + dt*16 + g*4) = u.h4v;
    }
  }
}

extern "C" void kernel_launch(void* const* d_in, const int* in_sizes, int n_in,
                              void* d_out, int out_size, void* d_ws, size_t ws_size,
                              hipStream_t stream) {
  const float* x    = (const float*)d_in[0];
  const int*   mask = (const int*)d_in[1];
  const float* Wqkv = (const float*)d_in[2];
  const float* bqkv = (const float*)d_in[3];
  const float* Wout = (const float*)d_in[4];
  const float* bout = (const float*)d_in[5];
  float* out = (float*)d_out;

  const size_t SZ_X    = (size_t)MTOT * DMODEL * 2;
  const size_t SZ_WQKV = (size_t)NQKV * DMODEL * 2;
  const size_t SZ_WOUT = (size_t)DMODEL * DMODEL * 2;
  const size_t SZ_QKV  = (size_t)BATCH * NHEADS * SEQ * DK * 2;
  const size_t SZ_MB   = (size_t)MTOT * 4 / 2;   // 2*2048 floats = 16KB
  const size_t NEED = SZ_X + SZ_WQKV + SZ_WOUT + 3*SZ_QKV + SZ_X + SZ_MB;
  if (ws_size < NEED) return;

  char* p = (char*)d_ws;
  f16* xh    = (f16*)p; p += SZ_X;
  f16* Wqkvt = (f16*)p; p += SZ_WQKV;
  f16* Woutt = (f16*)p; p += SZ_WOUT;
  f16* Qh    = (f16*)p; p += SZ_QKV;
  f16* Kh    = (f16*)p; p += SZ_QKV;
  f16* Vth   = (f16*)p; p += SZ_QKV;
  f16* ctx   = (f16*)p; p += SZ_X;
  float* mb  = (float*)p; p += SZ_MB;

  k_cvt<<<(MTOT*DMODEL)/(256*4), 256, 0, stream>>>(x, xh, MTOT*DMODEL);
  k_maskb<<<(BATCH*SEQ + 255)/256, 256, 0, stream>>>(mask, mb, BATCH*SEQ);
  k_tcvt<<<dim3(NQKV/32, DMODEL/32), dim3(32,8), 0, stream>>>(Wqkv, Wqkvt, DMODEL, NQKV);
  k_tcvt<<<dim3(DMODEL/32, DMODEL/32), dim3(32,8), 0, stream>>>(Wout, Woutt, DMODEL, DMODEL);

  k_gemm<0><<<dim3(NQKV/128, MTOT/128), 256, 0, stream>>>(
      xh, Wqkvt, bqkv, Qh, Kh, Vth, nullptr, MTOT, NQKV, DMODEL);

  k_attn5<<<32 * 32, 128, 0, stream>>>(Qh, Kh, Vth, mb, ctx);

  k_gemm<1><<<dim3(DMODEL/128, MTOT/128), 256, 0, stream>>>(
      ctx, Woutt, bout, nullptr, nullptr, nullptr, out, MTOT, DMODEL, DMODEL);
}